// Round 1
// baseline (135.638 us; speedup 1.0000x reference)
//
#include <hip/hip_runtime.h>

// LimbLength: out[b,k] = || in[b,k,:] - in[b,parent[k],:] ||_2
// in: (B=500000, K=15, D=3) float32, out: (B,15,1) float32.
// Memory-bound: 90 MB read + 30 MB write.

// LIMB_CONNECTION = [0,0,1,1,1,3,4,5,6,2,2,9,10,11,12] packed 4 bits/entry,
// entry k at bit 4k.
#define LIMB_PACK 0x0CBA922654311100ULL

__global__ __launch_bounds__(256) void limb_length_kernel(
    const float* __restrict__ in, float* __restrict__ out, int total) {
    int tid = blockIdx.x * blockDim.x + threadIdx.x;
    if (tid >= total) return;

    unsigned ut = (unsigned)tid;
    unsigned b = ut / 15u;            // compile-time-const divisor -> mulhi+shift
    unsigned k = ut - b * 15u;
    unsigned p = (unsigned)((LIMB_PACK >> (k * 4u)) & 0xFULL);

    const float* __restrict__ row = in + (size_t)b * 45u;
    // self joint (coalesced across the wave: k*3+d walks the row contiguously)
    float x0 = row[k * 3u + 0u];
    float y0 = row[k * 3u + 1u];
    float z0 = row[k * 3u + 2u];
    // parent joint (same 180B row -> L1 hit)
    float x1 = row[p * 3u + 0u];
    float y1 = row[p * 3u + 1u];
    float z1 = row[p * 3u + 2u];

    float dx = x0 - x1;
    float dy = y0 - y1;
    float dz = z0 - z1;
    out[tid] = sqrtf(dx * dx + dy * dy + dz * dz);
}

extern "C" void kernel_launch(void* const* d_in, const int* in_sizes, int n_in,
                              void* d_out, int out_size, void* d_ws, size_t ws_size,
                              hipStream_t stream) {
    const float* in = (const float*)d_in[0];
    float* out = (float*)d_out;
    int total = out_size;  // B*K = 7,500,000
    int block = 256;
    int grid = (total + block - 1) / block;
    limb_length_kernel<<<grid, block, 0, stream>>>(in, out, total);
}